// Round 7
// baseline (4227.635 us; speedup 1.0000x reference)
//
#include <hip/hip_runtime.h>
#include <hip/hip_bf16.h>
#include <stdint.h>

// RecognitionODEGRU R13 — 8 producers/chain, 512-thread blocks, W3 in regs.
// Scaling law from R10/R11: fabric phase cost ~ requester count (2x blocks at
// same bytes = 1.5x per-phase). R6's 16 n-blocks existed to halve per-block
// weight streaming; R12's register weights made that obsolete. R13 inverts:
// 128 blocks (16 chains x 8 n-blocks) x 512 threads. Per-wave profile is
// R12-identical (16-col slices, w1f 64 + w2f 128 VGPR); W3 moves LDS->regs
// (w3f[32], +128 VGPR; LDS drops to 66KB). Half the MALL requesters, half
// the publish train (8 RMWs), half the straggler pool, same bytes. nb==XCD
// exactly -> ~1MB weight set/XCD, 16-way reuse. Protocol R7/R12-verbatim
// with producer count 8 (targets step 8, cw pre-armed 8).
//
// Shapes: B=512, T=8, D=512, H=512, NSTEPS=4.
// d_out: outs[-1] (512,128) | h (512,512) | c=zeros (512,512), f32.

#define B_ 512
#define T_ 8
#define H_ 512
#define D_ 512

typedef short short8 __attribute__((ext_vector_type(8)));
typedef float f32x4 __attribute__((ext_vector_type(4)));
typedef __hip_bfloat16 bf16;
typedef unsigned long long u64;

__device__ __forceinline__ float sigm(float x){ return 1.f/(1.f+__expf(-x)); }

#define MFMA16(a,b,c) __builtin_amdgcn_mfma_f32_16x16x32_bf16((a),(b),(c),0,0,0)
#define ALD4(p)   __hip_atomic_load((p), __ATOMIC_RELAXED, __HIP_MEMORY_SCOPE_AGENT)
#define AST8(p,v) __hip_atomic_store((u64*)(p),(v),__ATOMIC_RELAXED,__HIP_MEMORY_SCOPE_AGENT)

__device__ __forceinline__ void wait_ge(unsigned* c, unsigned tgt, int* dead){
  if (threadIdx.x == 0){
    if (!*dead){
      int it = 0;
      while (ALD4(c) < tgt){
        __builtin_amdgcn_s_sleep(1);
        if (++it > 50000000){ *dead = 1; break; }  // terminate visibly, no hang
      }
    }
  }
  __syncthreads();
}
__device__ __forceinline__ void publish(unsigned* c){
  __builtin_amdgcn_s_waitcnt(0);   // each wave drains its stores before barrier
  __syncthreads();
  if (threadIdx.x == 0)
    __hip_atomic_fetch_add(c, 1u, __ATOMIC_RELAXED, __HIP_MEMORY_SCOPE_AGENT);
}

// Coherent slab stage (512 threads): CH 16B-chunks/thread, 2^SH chunks/row.
template<int CH, int SH>
__device__ __forceinline__ void stageC16(bf16* lds, int lstr, const bf16* g, int gstr){
  f32x4 tmp[CH];
#pragma unroll
  for (int j = 0; j < CH; ++j){
    int idx = j*512 + threadIdx.x;
    const bf16* p = g + (size_t)(idx >> SH)*gstr + (size_t)(idx & ((1<<SH)-1))*8;
    asm volatile("global_load_dwordx4 %0, %1, off sc0 sc1" : "=v"(tmp[j]) : "v"(p));
  }
  asm volatile("s_waitcnt vmcnt(0)" ::: "memory");
  __builtin_amdgcn_sched_barrier(0);   // keep ds_writes below the waitcnt
#pragma unroll
  for (int j = 0; j < CH; ++j){
    int idx = j*512 + threadIdx.x;
    *(f32x4*)&lds[(idx >> SH)*lstr + (idx & ((1<<SH)-1))*8] = tmp[j];
  }
}
// Plain (L2-cached) slab stage (512 threads).
template<int CH, int SH>
__device__ __forceinline__ void stageP(bf16* lds, int lstr, const bf16* g, size_t gstr){
#pragma unroll
  for (int j = 0; j < CH; ++j){
    int idx = j*512 + threadIdx.x;
    *(short8*)&lds[(idx >> SH)*lstr + (idx & ((1<<SH)-1))*8] =
        *(const short8*)(g + (size_t)(idx >> SH)*gstr + (size_t)(idx & ((1<<SH)-1))*8);
  }
}

__device__ __forceinline__ u64 pk4(float a0, float a1, float a2, float a3){
  union { bf16 h[4]; u64 q; } u;
  u.h[0] = __float2bfloat16(a0); u.h[1] = __float2bfloat16(a1);
  u.h[2] = __float2bfloat16(a2); u.h[3] = __float2bfloat16(a3);
  return u.q;
}

// LDS: slab 32x1032 @0 (66048B) | t0s/dts/tcs @66048 (384B) | dead @66432
__global__ __launch_bounds__(512, 1) void persist_k(
    const bf16* __restrict__ W1hb, const bf16* __restrict__ W2b,
    const bf16* __restrict__ W3b,  const bf16* __restrict__ Woutb,
    const bf16* __restrict__ Wc3,  const bf16* __restrict__ xbf,
    const float* __restrict__ b1,  const float* __restrict__ b2,
    const float* __restrict__ b3,  const float* __restrict__ bout,
    const float* __restrict__ bcb3,const float* __restrict__ w1t,
    const float* __restrict__ ts,
    bf16* wbuf, bf16* z1buf, bf16* z2buf,
    unsigned* cnts, float* dout)
{
  extern __shared__ char smem[];
  bf16* slab = (bf16*)smem;
  float* t0s = (float*)(smem + 66048);
  float* dts = t0s + 32;
  float* tcs = dts + 32;
  int* dead  = (int*)(smem + 66432);

  const int tid = threadIdx.x, lane = tid & 63, wv = tid >> 6;   // 8 waves
  const int fr = lane & 15, quad = lane >> 4;
  const int nb = blockIdx.x & 7;      // 8 n-blocks — nb == XCD (L2 residency)
  const int mb = blockIdx.x >> 3;     // 16 chains
  const int gm0 = mb * 32;
  const int wm = wv & 1;              // batch half (k/gates/final-h)
  const int wn = wv >> 1;             // 16-col quarter of 64 (k/gates/final-h)

  unsigned* cz1 = cnts + mb*128;
  unsigned* cz2 = cz1 + 32;
  unsigned* cw  = cz1 + 64;
  unsigned* cgt = cz1 + 96;

  if (tid < 32){
    float t0 = ts[(gm0 + tid)*T_];
    t0s[tid] = t0; tcs[tid] = t0; dts[tid] = 0.f;
  }
  if (tid == 0) *dead = 0;
  __syncthreads();

  // per-lane constant vectors (4 consecutive output cols: quad*4 + j)
  const int zc0 = 128*nb + 16*wv + quad*4;  // z-phase col base (8x16 N-slices)
  const int kc0 = 64*nb + 16*wn + quad*4;   // k/gates/final-h col base
  const f32x4 b1v  = *(const f32x4*)&b1[zc0];
  const f32x4 w1tv = *(const f32x4*)&w1t[zc0];
  const f32x4 b2v  = *(const f32x4*)&b2[zc0];
  const f32x4 b3v  = *(const f32x4*)&b3[kc0];
  // gate constants: hidden col hc = kc0(+j); Wc3 row R=(hc>>5)*128+g*32+(hc&31)
  const int gn16 = 2*nb + (wn >> 1);        // hc>>5
  const int gc   = 16*(wn & 1) + quad*4;    // hc&31 base
  f32x4 bcv[4];
#pragma unroll
  for (int g = 0; g < 4; ++g)
    bcv[g] = *(const f32x4*)&bcb3[gn16*128 + g*32 + gc];
  const f32x4 bov = *(const f32x4*)&bout[16*nb + quad*4];

  // weight row pointers
  const bf16* w1p = W1hb  + (size_t)(128*nb + 16*wv + fr)*512  + quad*8;
  const bf16* w2p = W2b   + (size_t)(128*nb + 16*wv + fr)*1024 + quad*8;
  const bf16* w3p = W3b   + (size_t)(64*nb + 16*wn + fr)*1024 + quad*8;
  const bf16* wop = Woutb + (size_t)(16*nb + fr)*512 + quad*8;
  const bf16* wcp[4];
#pragma unroll
  for (int g = 0; g < 4; ++g)
    wcp[g] = Wc3 + (size_t)(gn16*128 + g*32 + 16*(wn & 1) + fr)*1024 + quad*8;

  // ===== register-resident weight fragments (loop-invariant, 320 VGPR) =====
  short8 w1f[16], w2f[32], w3f[32];
#pragma unroll
  for (int k = 0; k < 16; ++k) w1f[k] = *(const short8*)(w1p + k*32);
#pragma unroll
  for (int k = 0; k < 32; ++k) w2f[k] = *(const short8*)(w2p + k*32);
#pragma unroll
  for (int k = 0; k < 32; ++k) w3f[k] = *(const short8*)(w3p + k*32);

  float hreg[4] = {0,0,0,0}, kacc[4] = {0,0,0,0};
  unsigned tz1 = 8, tz2 = 8, tw = 8, tg = 8;

  for (int s = 0; s < T_; ++s){
    for (int sub = 0; sub < 4; ++sub){
      for (int e = 1; e <= 4; ++e){
        // ===== z1 = swish(w @ W1^T + t*w1t + b1), M32 N128 K512 =====
        wait_ge(cw, tw, dead);
        stageC16<4,6>(slab, 520, wbuf + (size_t)gm0*512, 512);
        __syncthreads();
        {
          f32x4 a0 = {0,0,0,0}, a1 = {0,0,0,0};
#pragma unroll
          for (int k = 0; k < 16; ++k){
            a0 = MFMA16(w1f[k], *(const short8*)&slab[fr*520      + k*32 + quad*8], a0);
            a1 = MFMA16(w1f[k], *(const short8*)&slab[(16+fr)*520 + k*32 + quad*8], a1);
          }
          float t0v = tcs[fr], t1v = tcs[16 + fr];
          float s0[4], s1[4];
#pragma unroll
          for (int j = 0; j < 4; ++j){
            float v0 = a0[j] + b1v[j] + t0v*w1tv[j];
            float v1 = a1[j] + b1v[j] + t1v*w1tv[j];
            s0[j] = v0*sigm(v0); s1[j] = v1*sigm(v1);
          }
          AST8(z1buf + (size_t)(gm0 + fr)*1024 + zc0,      pk4(s0[0],s0[1],s0[2],s0[3]));
          AST8(z1buf + (size_t)(gm0 + 16 + fr)*1024 + zc0, pk4(s1[0],s1[1],s1[2],s1[3]));
          publish(cz1);
        }
        // ===== z2 = swish(z1 @ W2^T + b2), M32 N128 K1024 =====
        wait_ge(cz1, tz1, dead); tz1 += 8;
        stageC16<8,7>(slab, 1032, z1buf + (size_t)gm0*1024, 1024);
        __syncthreads();
        {
          f32x4 a0 = {0,0,0,0}, a1 = {0,0,0,0};
#pragma unroll
          for (int k = 0; k < 32; ++k){
            a0 = MFMA16(w2f[k], *(const short8*)&slab[fr*1032      + k*32 + quad*8], a0);
            a1 = MFMA16(w2f[k], *(const short8*)&slab[(16+fr)*1032 + k*32 + quad*8], a1);
          }
          float s0[4], s1[4];
#pragma unroll
          for (int j = 0; j < 4; ++j){
            float v0 = a0[j] + b2v[j], v1 = a1[j] + b2v[j];
            s0[j] = v0*sigm(v0); s1[j] = v1*sigm(v1);
          }
          AST8(z2buf + (size_t)(gm0 + fr)*1024 + zc0,      pk4(s0[0],s0[1],s0[2],s0[3]));
          AST8(z2buf + (size_t)(gm0 + 16 + fr)*1024 + zc0, pk4(s1[0],s1[1],s1[2],s1[3]));
          publish(cz2);
        }
        // ===== k = z2 @ W3^T + b3 ; RK4 in registers, M32 N64 K1024 =====
        wait_ge(cz2, tz2, dead); tz2 += 8;
        stageC16<8,7>(slab, 1032, z2buf + (size_t)gm0*1024, 1024);
        __syncthreads();
        {
          f32x4 ak = {0,0,0,0};
#pragma unroll
          for (int k = 0; k < 32; ++k){
            ak = MFMA16(w3f[k],
                        *(const short8*)&slab[(wm*16 + fr)*1032 + k*32 + quad*8], ak);
          }
          const int r = wm*16 + fr;
          const float dtv = dts[r];
          float w4[4];
#pragma unroll
          for (int j = 0; j < 4; ++j){
            float v = ak[j] + b3v[j];
            float ka = (e == 1) ? v : kacc[j] + ((e == 4) ? 1.f : 2.f)*v;
            if (e < 4){ kacc[j] = ka; w4[j] = hreg[j] + ((e == 3) ? 1.f : 0.5f)*dtv*v; }
            else      { hreg[j] = hreg[j] + dtv*(1.f/6.f)*ka; w4[j] = hreg[j]; }
          }
          AST8(wbuf + (size_t)(gm0 + r)*512 + kc0, pk4(w4[0],w4[1],w4[2],w4[3]));
          if (tid < 32){
            float ce = (e <= 2) ? ((float)sub + 0.5f) : ((float)sub + 1.f);
            tcs[tid] = t0s[tid] + dts[tid]*ce;
          }
          publish(cw); tw += 8;
        }
      }
    }
    // ===== gates: [w|x_s] @ Wc3^T (4 groups r|z|hn|in x 64 cols), K=1024 =====
    wait_ge(cw, tw, dead);
    stageC16<4,6>(slab, 1032, wbuf + (size_t)gm0*512, 512);
    stageP<4,6>(slab + 512, 1032, xbf + ((size_t)gm0*T_ + s)*512, (size_t)T_*512);
    __syncthreads();
    publish(cgt);   // old w consumed (staged); safe to overwrite after all 8 publish
    {
      f32x4 ag[4] = {{0,0,0,0},{0,0,0,0},{0,0,0,0},{0,0,0,0}};
#pragma unroll 4
      for (int k = 0; k < 32; ++k){
        short8 xv = *(const short8*)&slab[(wm*16 + fr)*1032 + k*32 + quad*8];
#pragma unroll
        for (int g = 0; g < 4; ++g)
          ag[g] = MFMA16(*(const short8*)(wcp[g] + k*32), xv, ag[g]);
      }
      wait_ge(cgt, tg, dead); tg += 8;
      const int r = wm*16 + fr;
#pragma unroll
      for (int j = 0; j < 4; ++j){
        float r_ = sigm(ag[0][j] + bcv[0][j]);
        float z_ = sigm(ag[1][j] + bcv[1][j]);
        float hn = ag[2][j] + bcv[2][j];
        float in = ag[3][j] + bcv[3][j];
        float n_ = tanhf(in + r_*hn);
        hreg[j] = (1.f - z_)*n_ + z_*hreg[j];
      }
      AST8(wbuf + (size_t)(gm0 + r)*512 + kc0, pk4(hreg[0],hreg[1],hreg[2],hreg[3]));
      if (tid < 32){
        float t0n = ts[(gm0 + tid)*T_ + s];
        float t1  = (s < T_-1) ? ts[(gm0 + tid)*T_ + s + 1] : t0n;
        t0s[tid] = t0n; tcs[tid] = t0n; dts[tid] = (t1 - t0n)*0.25f;
      }
      publish(cw); tw += 8;
    }
  }
  // ===== final: out = h @ Wout^T + bout ; h ; c = 0 =====
  wait_ge(cw, tw, dead);
  stageC16<4,6>(slab, 520, wbuf + (size_t)gm0*512, 512);
  __syncthreads();
  if (wv < 2){   // 8 n-blocks x 16 cols cover the 128 outs; wv = batch half
    f32x4 ao = {0,0,0,0};
#pragma unroll 4
    for (int k = 0; k < 16; ++k){
      ao = MFMA16(*(const short8*)(wop + k*32),
                  *(const short8*)&slab[(wv*16 + fr)*520 + k*32 + quad*8], ao);
    }
    f32x4 o;
#pragma unroll
    for (int j = 0; j < 4; ++j) o[j] = ao[j] + bov[j];
    *(f32x4*)&dout[(size_t)(gm0 + wv*16 + fr)*128 + 16*nb + quad*4] = o;
  }
  {
    const int r = wm*16 + fr;
    f32x4 hv; hv[0]=hreg[0]; hv[1]=hreg[1]; hv[2]=hreg[2]; hv[3]=hreg[3];
    *(f32x4*)&dout[(size_t)B_*128 + (size_t)(gm0 + r)*512 + kc0] = hv;
    f32x4 z4 = {0,0,0,0};
    *(f32x4*)&dout[(size_t)B_*128 + (size_t)B_*512 + (size_t)(gm0 + r)*512 + kc0] = z4;
  }
}

// ---- prolog kernels ----
__global__ void conv_k(const float* __restrict__ in, bf16* __restrict__ out,
                       int rows, int kin, int kout)
{
  int idx = blockIdx.x*256 + threadIdx.x;
  if (idx >= rows*kout) return;
  int r = idx / kout, k = idx - r*kout;
  out[idx] = __float2bfloat16(k < kin ? in[(size_t)r*kin + k] : 0.f);
}

__global__ void w1t_k(const float* __restrict__ W1, float* __restrict__ w1t)
{
  int i = blockIdx.x*256 + threadIdx.x;
  if (i < 1024) w1t[i] = W1[(size_t)i*513 + 512];
}

// Wc3 row R = n16*128 + g*32 + c; hidden col hc = n16*32 + c.
// K: [0:512]=h-part, [512:1024]=x-part. g=0:r g=1:z g=2:hn=[Whh_n|0] g=3:in=[0|Wih_n].
__global__ void wc3_k(const float* __restrict__ Wih, const float* __restrict__ Whh,
                      const float* __restrict__ bih, const float* __restrict__ bhh,
                      bf16* __restrict__ Wc3, float* __restrict__ bcb3)
{
  int idx = blockIdx.x*256 + threadIdx.x;
  if (idx >= 2048*1024) return;
  int R = idx >> 10, k = idx & 1023;
  int n16 = R >> 7, g = (R >> 5) & 3, c = R & 31;
  int hc = n16*32 + c;
  float v;
  if      (g == 0) v = (k < 512) ? Whh[(size_t)hc*512 + k]        : Wih[(size_t)hc*512 + k - 512];
  else if (g == 1) v = (k < 512) ? Whh[(size_t)(512+hc)*512 + k]  : Wih[(size_t)(512+hc)*512 + k - 512];
  else if (g == 2) v = (k < 512) ? Whh[(size_t)(1024+hc)*512 + k] : 0.f;
  else             v = (k < 512) ? 0.f                             : Wih[(size_t)(1024+hc)*512 + k - 512];
  Wc3[idx] = __float2bfloat16(v);
  if (k == 0){
    if      (g == 0) bcb3[R] = bih[hc] + bhh[hc];
    else if (g == 1) bcb3[R] = bih[512 + hc] + bhh[512 + hc];
    else if (g == 2) bcb3[R] = bhh[1024 + hc];
    else             bcb3[R] = bih[1024 + hc];
  }
}

__global__ void init_k(bf16* __restrict__ wbuf, unsigned* __restrict__ cnts)
{
  int idx = blockIdx.x*256 + threadIdx.x;
  if (idx < B_*H_) wbuf[idx] = __float2bfloat16(0.f);
  if (idx < 16*128){
    int off = idx & 127;
    cnts[idx] = (off == 64) ? 8u : 0u;   // cw pre-armed (initial w=0 published)
  }
}

extern "C" void kernel_launch(void* const* d_in, const int* in_sizes, int n_in,
                              void* d_out, int out_size, void* d_ws, size_t ws_size,
                              hipStream_t stream)
{
  const float* x    = (const float*)d_in[0];
  const float* ts   = (const float*)d_in[1];
  const float* Wih  = (const float*)d_in[2];
  const float* Whh  = (const float*)d_in[3];
  const float* bih  = (const float*)d_in[4];
  const float* bhh  = (const float*)d_in[5];
  const float* Wout = (const float*)d_in[6];
  const float* bout = (const float*)d_in[7];
  const float* W1   = (const float*)d_in[8];
  const float* b1   = (const float*)d_in[9];
  const float* W2   = (const float*)d_in[10];
  const float* b2   = (const float*)d_in[11];
  const float* W3   = (const float*)d_in[12];
  const float* b3   = (const float*)d_in[13];

  char* ws = (char*)d_ws;
  size_t off = 0;
  auto alloc = [&](size_t n){ void* p = ws + off; off += (n + 255) & ~(size_t)255; return p; };

  bf16* xbf   = (bf16*)alloc((size_t)B_*T_*D_*2);
  bf16* W1hb  = (bf16*)alloc((size_t)1024*512*2);
  bf16* W2b   = (bf16*)alloc((size_t)1024*1024*2);
  bf16* W3b   = (bf16*)alloc((size_t)512*1024*2);
  bf16* Woutb = (bf16*)alloc((size_t)128*512*2);
  bf16* Wc3   = (bf16*)alloc((size_t)2048*1024*2);
  float* bcb3 = (float*)alloc((size_t)2048*4);
  float* w1t  = (float*)alloc((size_t)1024*4);
  bf16* wbuf  = (bf16*)alloc((size_t)B_*H_*2);
  bf16* z1buf = (bf16*)alloc((size_t)B_*1024*2);
  bf16* z2buf = (bf16*)alloc((size_t)B_*1024*2);
  unsigned* cnts = (unsigned*)alloc((size_t)16*128*4);

  auto conv = [&](const float* in, bf16* out, int rows, int kin, int kout){
    int n = rows*kout;
    conv_k<<<(n + 255)/256, 256, 0, stream>>>(in, out, rows, kin, kout);
  };
  conv(x, xbf, B_*T_, D_, D_);
  conv(W1, W1hb, 1024, 513, 512);   // col 512 handled via w1t rank-1 term
  conv(W2, W2b, 1024, 1024, 1024);
  conv(W3, W3b, 512, 1024, 1024);
  conv(Wout, Woutb, 128, 512, 512);
  w1t_k<<<4, 256, 0, stream>>>(W1, w1t);
  wc3_k<<<(2048*1024)/256, 256, 0, stream>>>(Wih, Whh, bih, bhh, Wc3, bcb3);
  init_k<<<(B_*H_ + 255)/256, 256, 0, stream>>>(wbuf, cnts);

  (void)hipFuncSetAttribute((const void*)persist_k,
                            hipFuncAttributeMaxDynamicSharedMemorySize, 66560);
  persist_k<<<128, 512, 66560, stream>>>(
      W1hb, W2b, W3b, Woutb, Wc3, xbf,
      b1, b2, b3, bout, bcb3, w1t, ts,
      wbuf, z1buf, z2buf, cnts, (float*)d_out);
}

// Round 8
// 1821.761 us; speedup vs baseline: 2.3206x; 2.3206x over previous
//
#include <hip/hip_runtime.h>
#include <hip/hip_bf16.h>
#include <stdint.h>

// RecognitionODEGRU R14 — RK4 in the W1-transformed domain (phase fusion).
// R13 lesson: 512-thr blocks cap VGPR at 256 -> spill; register weights need
// 256-thr/1-wave-per-SIMD (R12). R14 keeps R12's topology (16 chains x 16
// blocks x 256 thr, MALL handshake) and cuts SERIAL PHASES 393 -> ~274:
//   k-phase + next z1-phase fuse via Wf = W1h@W3 (precomputed):
//   z1pre_next = hW + c*dt*(z2@Wf^T + bf3) + tc*w1t + b1,  hW = h@W1h^T.
// Per eval: A (z2 = swish(z1@W2^T+b2), ZACC += wgt*z2) and B (P = z2@Wf^T,
// emit next z1s; at e=4 update hW += dt/6*PACC + dt*bf3). Per timestep:
// h-mat (h += dt/6*ZACC@W3^T + 4dt*b3), gates (GRU), hW (h'@W1h^T, emit z1s).
// Counters: cz1 (z1buf writers: init/B/hW), cz2 (A), ch (h-mat), cg (gates).
// Hazard audit: z1buf overwritten in B(e) only after cz2>=all A(e) (A staged
// z1); z2buf in A(e+1) after cz1>=all B(e); zbuf/hbuf/wbuf cycles close
// transitively through ch/cg/cz1 (each consumer stage precedes its publish).
//
// Shapes: B=512, T=8, D=512, H=512, NSTEPS=4.
// d_out: outs[-1] (512,128) | h (512,512) | c=zeros (512,512), f32.

#define B_ 512
#define T_ 8
#define H_ 512
#define D_ 512

typedef short short8 __attribute__((ext_vector_type(8)));
typedef float f32x4 __attribute__((ext_vector_type(4)));
typedef __hip_bfloat16 bf16;
typedef unsigned long long u64;

__device__ __forceinline__ float sigm(float x){ return 1.f/(1.f+__expf(-x)); }

#define MFMA16(a,b,c) __builtin_amdgcn_mfma_f32_16x16x32_bf16((a),(b),(c),0,0,0)
#define ALD4(p)   __hip_atomic_load((p), __ATOMIC_RELAXED, __HIP_MEMORY_SCOPE_AGENT)
#define AST8(p,v) __hip_atomic_store((u64*)(p),(v),__ATOMIC_RELAXED,__HIP_MEMORY_SCOPE_AGENT)

__device__ __forceinline__ void wait_ge(unsigned* c, unsigned tgt, int* dead){
  if (threadIdx.x == 0){
    if (!*dead){
      int it = 0;
      while (ALD4(c) < tgt){
        __builtin_amdgcn_s_sleep(1);
        if (++it > 50000000){ *dead = 1; break; }  // terminate visibly, no hang
      }
    }
  }
  __syncthreads();
}
__device__ __forceinline__ void publish(unsigned* c){
  __builtin_amdgcn_s_waitcnt(0);   // each wave drains its stores before barrier
  __syncthreads();
  if (threadIdx.x == 0)
    __hip_atomic_fetch_add(c, 1u, __ATOMIC_RELAXED, __HIP_MEMORY_SCOPE_AGENT);
}

// Coherent slab stage: CH 16B-chunks/thread, 2^SH chunks per row (MALL path).
template<int CH, int SH>
__device__ __forceinline__ void stageC16(bf16* lds, int lstr, const bf16* g, int gstr){
  f32x4 tmp[CH];
#pragma unroll
  for (int j = 0; j < CH; ++j){
    int idx = j*256 + threadIdx.x;
    const bf16* p = g + (size_t)(idx >> SH)*gstr + (size_t)(idx & ((1<<SH)-1))*8;
    asm volatile("global_load_dwordx4 %0, %1, off sc0 sc1" : "=v"(tmp[j]) : "v"(p));
  }
  asm volatile("s_waitcnt vmcnt(0)" ::: "memory");
  __builtin_amdgcn_sched_barrier(0);   // keep ds_writes below the waitcnt
#pragma unroll
  for (int j = 0; j < CH; ++j){
    int idx = j*256 + threadIdx.x;
    *(f32x4*)&lds[(idx >> SH)*lstr + (idx & ((1<<SH)-1))*8] = tmp[j];
  }
}
// Plain (L2-cached) slab stage: CH 16B-chunks/thread, 2^SH chunks per row.
template<int CH, int SH>
__device__ __forceinline__ void stageP(bf16* lds, int lstr, const bf16* g, size_t gstr){
#pragma unroll
  for (int j = 0; j < CH; ++j){
    int idx = j*256 + threadIdx.x;
    *(short8*)&lds[(idx >> SH)*lstr + (idx & ((1<<SH)-1))*8] =
        *(const short8*)(g + (size_t)(idx >> SH)*gstr + (size_t)(idx & ((1<<SH)-1))*8);
  }
}

__device__ __forceinline__ u64 pk4(float a0, float a1, float a2, float a3){
  union { bf16 h[4]; u64 q; } u;
  u.h[0] = __float2bfloat16(a0); u.h[1] = __float2bfloat16(a1);
  u.h[2] = __float2bfloat16(a2); u.h[3] = __float2bfloat16(a3);
  return u.q;
}

// LDS: slab 32x1032 @0 (66048B) | t0s @66048 | dts @66176 | dead @66304
__global__ __launch_bounds__(256, 1) void persist_k(
    const bf16* __restrict__ W1hb, const bf16* __restrict__ W2b,
    const bf16* __restrict__ Wfb,  const bf16* __restrict__ W3b,
    const bf16* __restrict__ Woutb,const bf16* __restrict__ Wc3,
    const bf16* __restrict__ xbf,
    const float* __restrict__ b1,  const float* __restrict__ b2,
    const float* __restrict__ b3,  const float* __restrict__ bout,
    const float* __restrict__ bcb3,const float* __restrict__ w1t,
    const float* __restrict__ bf3, const float* __restrict__ ts,
    bf16* wbuf, bf16* hbuf, bf16* z1buf, bf16* z2buf, bf16* zbuf,
    unsigned* cnts, float* dout)
{
  extern __shared__ char smem[];
  bf16* slab = (bf16*)smem;
  float* t0s = (float*)(smem + 66048);
  float* dts = (float*)(smem + 66176);
  int* dead  = (int*)(smem + 66304);

  const int tid = threadIdx.x, lane = tid & 63, wv = tid >> 6;
  const int fr = lane & 15, quad = lane >> 4;
  const int nb = blockIdx.x & 15;
  const int mb = blockIdx.x >> 4;     // 16 chains
  const int gm0 = mb * 32;
  const int wm = wv & 1;              // batch half (h-mat/gates)
  const int wn = wv >> 1;             // 16-col half (h-mat/gates)

  unsigned* cz1 = cnts + mb*128;
  unsigned* cz2 = cz1 + 32;
  unsigned* ch  = cz1 + 64;
  unsigned* cg  = cz1 + 96;

  if (tid < 32){
    float t0 = ts[(gm0 + tid)*T_];
    t0s[tid] = t0; dts[tid] = 0.f;   // timestep 0: t0==t1 -> dt=0 (reference)
  }
  if (tid == 0) *dead = 0;
  __syncthreads();

  // per-lane constant vectors (4 consecutive output cols: quad*4 + j)
  const int zc0 = 64*nb + 16*wv + quad*4;   // z-domain col base (per-wave)
  const int kc0 = 32*nb + 16*wn + quad*4;   // h-domain col base
  const f32x4 b1v  = *(const f32x4*)&b1[zc0];
  const f32x4 w1tv = *(const f32x4*)&w1t[zc0];
  const f32x4 b2v  = *(const f32x4*)&b2[zc0];
  const f32x4 bf3v = *(const f32x4*)&bf3[zc0];
  const f32x4 b3v  = *(const f32x4*)&b3[kc0];
  f32x4 bcv[4];
#pragma unroll
  for (int g = 0; g < 4; ++g)
    bcv[g] = *(const f32x4*)&bcb3[nb*128 + g*32 + 16*wn + quad*4];
  const f32x4 bov = *(const f32x4*)&bout[16*(nb & 7) + quad*4];

  // weight row pointers
  const bf16* w1p = W1hb  + (size_t)(64*nb + 16*wv + fr)*512  + quad*8;  // hW phase (streamed)
  const bf16* w2p = W2b   + (size_t)(64*nb + 16*wv + fr)*1024 + quad*8;  // -> regs
  const bf16* wfp = Wfb   + (size_t)(64*nb + 16*wv + fr)*1024 + quad*8;  // -> regs
  const bf16* w3p = W3b   + (size_t)(32*nb + 16*wn + fr)*1024 + quad*8;  // h-mat (streamed)
  const bf16* wop = Woutb + (size_t)(16*(nb & 7) + fr)*512 + quad*8;
  const bf16* wcp[4];
#pragma unroll
  for (int g = 0; g < 4; ++g)
    wcp[g] = Wc3 + (size_t)(nb*128 + g*32 + 16*wn + fr)*1024 + quad*8;

  // ===== register-resident weight fragments (loop-invariant, 256 VGPR) =====
  short8 w2f[32], wff[32];
#pragma unroll
  for (int k = 0; k < 32; ++k) w2f[k] = *(const short8*)(w2p + k*32);
#pragma unroll
  for (int k = 0; k < 32; ++k) wff[k] = *(const short8*)(wfp + k*32);

  // transformed-domain state (per lane: rows fr / 16+fr, cols zc0..+4)
  float hw0[4]={0,0,0,0}, hw1[4]={0,0,0,0};
  float pacc0[4]={0,0,0,0}, pacc1[4]={0,0,0,0};
  float zacc0[4]={0,0,0,0}, zacc1[4]={0,0,0,0};
  float hreg[4]={0,0,0,0};   // h-domain (row wm*16+fr, cols kc0..+4)
  unsigned tz1 = 16, tz2 = 16, tch = 16, tcg = 16;

  // initial z1s (h=0 -> hW=0): z1pre = t0*w1t + b1
  {
    const float t0a = t0s[fr], t0b = t0s[16 + fr];
    float v0[4], v1[4];
#pragma unroll
    for (int j = 0; j < 4; ++j){
      v0[j] = t0a*w1tv[j] + b1v[j];
      v1[j] = t0b*w1tv[j] + b1v[j];
      v0[j] *= sigm(v0[j]); v1[j] *= sigm(v1[j]);
    }
    AST8(z1buf + (size_t)(gm0 + fr)*1024 + zc0,      pk4(v0[0],v0[1],v0[2],v0[3]));
    AST8(z1buf + (size_t)(gm0 + 16 + fr)*1024 + zc0, pk4(v1[0],v1[1],v1[2],v1[3]));
    publish(cz1);
  }

  for (int s = 0; s < T_; ++s){
    for (int sub = 0; sub < 4; ++sub){
      for (int e = 1; e <= 4; ++e){
        // ===== A: z2 = swish(z1s @ W2^T + b2); ZACC += wgt*z2 =====
        wait_ge(cz1, tz1, dead); tz1 += 16;
        stageC16<16,7>(slab, 1032, z1buf + (size_t)gm0*1024, 1024);
        __syncthreads();
        {
          f32x4 a0 = {0,0,0,0}, a1 = {0,0,0,0};
#pragma unroll
          for (int k = 0; k < 32; ++k){
            a0 = MFMA16(w2f[k], *(const short8*)&slab[fr*1032      + k*32 + quad*8], a0);
            a1 = MFMA16(w2f[k], *(const short8*)&slab[(16+fr)*1032 + k*32 + quad*8], a1);
          }
          const float wgt = (e == 2 || e == 3) ? 2.f : 1.f;
          float s0[4], s1[4];
#pragma unroll
          for (int j = 0; j < 4; ++j){
            float v0 = a0[j] + b2v[j], v1 = a1[j] + b2v[j];
            s0[j] = v0*sigm(v0); s1[j] = v1*sigm(v1);
            zacc0[j] += wgt*s0[j]; zacc1[j] += wgt*s1[j];
          }
          if (sub == 3 && e == 4){
            AST8(zbuf + (size_t)(gm0 + fr)*1024 + zc0,      pk4(zacc0[0],zacc0[1],zacc0[2],zacc0[3]));
            AST8(zbuf + (size_t)(gm0 + 16 + fr)*1024 + zc0, pk4(zacc1[0],zacc1[1],zacc1[2],zacc1[3]));
#pragma unroll
            for (int j = 0; j < 4; ++j){ zacc0[j] = 0.f; zacc1[j] = 0.f; }
          } else {
            AST8(z2buf + (size_t)(gm0 + fr)*1024 + zc0,      pk4(s0[0],s0[1],s0[2],s0[3]));
            AST8(z2buf + (size_t)(gm0 + 16 + fr)*1024 + zc0, pk4(s1[0],s1[1],s1[2],s1[3]));
          }
          publish(cz2);
        }
        // ===== B: P = z2s @ Wf^T ; emit z1s_{e+1} (skip at sub3,e4) =====
        if (!(sub == 3 && e == 4)){
          wait_ge(cz2, tz2, dead); tz2 += 16;
          stageC16<16,7>(slab, 1032, z2buf + (size_t)gm0*1024, 1024);
          __syncthreads();
          f32x4 p0 = {0,0,0,0}, p1 = {0,0,0,0};
#pragma unroll
          for (int k = 0; k < 32; ++k){
            p0 = MFMA16(wff[k], *(const short8*)&slab[fr*1032      + k*32 + quad*8], p0);
            p1 = MFMA16(wff[k], *(const short8*)&slab[(16+fr)*1032 + k*32 + quad*8], p1);
          }
          const float dta = dts[fr], dtb = dts[16 + fr];
          const float t0a = t0s[fr], t0b = t0s[16 + fr];
          const float ce = (e <= 2) ? (float)sub + 0.5f : (float)sub + 1.f;
          float v0[4], v1[4];
          if (e < 4){
            const float c = (e == 3) ? 1.f : 0.5f;
            const float wgt = (e == 2 || e == 3) ? 2.f : 1.f;
            if (sub < 3){
#pragma unroll
              for (int j = 0; j < 4; ++j){ pacc0[j] += wgt*p0[j]; pacc1[j] += wgt*p1[j]; }
            }
#pragma unroll
            for (int j = 0; j < 4; ++j){
              v0[j] = hw0[j] + c*dta*(p0[j] + bf3v[j]) + (t0a + dta*ce)*w1tv[j] + b1v[j];
              v1[j] = hw1[j] + c*dtb*(p1[j] + bf3v[j]) + (t0b + dtb*ce)*w1tv[j] + b1v[j];
            }
          } else {   // e==4 (only sub<3): advance hW to next sub-step
#pragma unroll
            for (int j = 0; j < 4; ++j){
              float pa = pacc0[j] + p0[j], pb = pacc1[j] + p1[j];
              hw0[j] += dta*(1.f/6.f)*pa + dta*bf3v[j];
              hw1[j] += dtb*(1.f/6.f)*pb + dtb*bf3v[j];
              pacc0[j] = 0.f; pacc1[j] = 0.f;
              v0[j] = hw0[j] + (t0a + dta*ce)*w1tv[j] + b1v[j];
              v1[j] = hw1[j] + (t0b + dtb*ce)*w1tv[j] + b1v[j];
            }
          }
#pragma unroll
          for (int j = 0; j < 4; ++j){ v0[j] *= sigm(v0[j]); v1[j] *= sigm(v1[j]); }
          AST8(z1buf + (size_t)(gm0 + fr)*1024 + zc0,      pk4(v0[0],v0[1],v0[2],v0[3]));
          AST8(z1buf + (size_t)(gm0 + 16 + fr)*1024 + zc0, pk4(v1[0],v1[1],v1[2],v1[3]));
          publish(cz1);
        }
      }
    }
    // ===== h-mat: h += dt/6 * ZACC@W3^T + 4dt*b3 =====
    wait_ge(cz2, tz2, dead); tz2 += 16;
    stageC16<16,7>(slab, 1032, zbuf + (size_t)gm0*1024, 1024);
    __syncthreads();
    {
      f32x4 ak = {0,0,0,0};
#pragma unroll 8
      for (int k = 0; k < 32; ++k){
        ak = MFMA16(*(const short8*)(w3p + k*32),
                    *(const short8*)&slab[(wm*16 + fr)*1032 + k*32 + quad*8], ak);
      }
      const int r = wm*16 + fr;
      const float dtv = dts[r];
#pragma unroll
      for (int j = 0; j < 4; ++j)
        hreg[j] = hreg[j] + dtv*(1.f/6.f)*ak[j] + 4.f*dtv*b3v[j];
      AST8(hbuf + (size_t)(gm0 + r)*512 + kc0, pk4(hreg[0],hreg[1],hreg[2],hreg[3]));
      publish(ch);
    }
    // ===== gates: [h|x_s] @ Wc3^T ; GRU update =====
    wait_ge(ch, tch, dead); tch += 16;
    stageC16<8,6>(slab, 1032, hbuf + (size_t)gm0*512, 512);
    stageP<8,6>(slab + 512, 1032, xbf + ((size_t)gm0*T_ + s)*512, (size_t)T_*512);
    __syncthreads();
    {
      f32x4 ag[4] = {{0,0,0,0},{0,0,0,0},{0,0,0,0},{0,0,0,0}};
#pragma unroll 4
      for (int k = 0; k < 32; ++k){
        short8 xv = *(const short8*)&slab[(wm*16 + fr)*1032 + k*32 + quad*8];
#pragma unroll
        for (int g = 0; g < 4; ++g)
          ag[g] = MFMA16(*(const short8*)(wcp[g] + k*32), xv, ag[g]);
      }
      const int r = wm*16 + fr;
#pragma unroll
      for (int j = 0; j < 4; ++j){
        float r_ = sigm(ag[0][j] + bcv[0][j]);
        float z_ = sigm(ag[1][j] + bcv[1][j]);
        float hn = ag[2][j] + bcv[2][j];
        float in = ag[3][j] + bcv[3][j];
        float n_ = tanhf(in + r_*hn);
        hreg[j] = (1.f - z_)*n_ + z_*hreg[j];
      }
      AST8(wbuf + (size_t)(gm0 + r)*512 + kc0, pk4(hreg[0],hreg[1],hreg[2],hreg[3]));
      if (s == T_-1){   // final h (f32 exact) and c=0
        f32x4 hv; hv[0]=hreg[0]; hv[1]=hreg[1]; hv[2]=hreg[2]; hv[3]=hreg[3];
        *(f32x4*)&dout[(size_t)B_*128 + (size_t)(gm0 + r)*512 + kc0] = hv;
        f32x4 z4 = {0,0,0,0};
        *(f32x4*)&dout[(size_t)B_*128 + (size_t)B_*512 + (size_t)(gm0 + r)*512 + kc0] = z4;
      }
      if (tid < 32){
        float t0n = ts[(gm0 + tid)*T_ + s];
        float t1  = (s < T_-1) ? ts[(gm0 + tid)*T_ + s + 1] : t0n;
        t0s[tid] = t0n; dts[tid] = (t1 - t0n)*0.25f;
      }
      publish(cg);
    }
    // ===== hW: hW = h' @ W1h^T ; emit z1s for next timestep =====
    if (s < T_-1){
      wait_ge(cg, tcg, dead); tcg += 16;
      stageC16<8,6>(slab, 520, wbuf + (size_t)gm0*512, 512);
      __syncthreads();
      f32x4 a0 = {0,0,0,0}, a1 = {0,0,0,0};
#pragma unroll 4
      for (int k = 0; k < 16; ++k){
        short8 wt = *(const short8*)(w1p + k*32);
        a0 = MFMA16(wt, *(const short8*)&slab[fr*520      + k*32 + quad*8], a0);
        a1 = MFMA16(wt, *(const short8*)&slab[(16+fr)*520 + k*32 + quad*8], a1);
      }
      const float t0a = t0s[fr], t0b = t0s[16 + fr];
      float v0[4], v1[4];
#pragma unroll
      for (int j = 0; j < 4; ++j){
        hw0[j] = a0[j]; hw1[j] = a1[j];
        v0[j] = hw0[j] + t0a*w1tv[j] + b1v[j];
        v1[j] = hw1[j] + t0b*w1tv[j] + b1v[j];
        v0[j] *= sigm(v0[j]); v1[j] *= sigm(v1[j]);
      }
      AST8(z1buf + (size_t)(gm0 + fr)*1024 + zc0,      pk4(v0[0],v0[1],v0[2],v0[3]));
      AST8(z1buf + (size_t)(gm0 + 16 + fr)*1024 + zc0, pk4(v1[0],v1[1],v1[2],v1[3]));
      publish(cz1);
    }
  }
  // ===== final: out = h' @ Wout^T + bout (h,c written in last gates) =====
  wait_ge(cg, tcg, dead); tcg += 16;
  stageC16<8,6>(slab, 520, wbuf + (size_t)gm0*512, 512);
  __syncthreads();
  if (nb < 8 && wv < 2){   // 8 n-blocks x 16 cols cover the 128 outs
    f32x4 ao = {0,0,0,0};
#pragma unroll 4
    for (int k = 0; k < 16; ++k){
      ao = MFMA16(*(const short8*)(wop + k*32),
                  *(const short8*)&slab[(wv*16 + fr)*520 + k*32 + quad*8], ao);
    }
    f32x4 o;
#pragma unroll
    for (int j = 0; j < 4; ++j) o[j] = ao[j] + bov[j];
    *(f32x4*)&dout[(size_t)(gm0 + wv*16 + fr)*128 + 16*nb + quad*4] = o;
  }
}

// ---- prolog kernels ----
__global__ void conv_k(const float* __restrict__ in, bf16* __restrict__ out,
                       int rows, int kin, int kout)
{
  int idx = blockIdx.x*256 + threadIdx.x;
  if (idx >= rows*kout) return;
  int r = idx / kout, k = idx - r*kout;
  out[idx] = __float2bfloat16(k < kin ? in[(size_t)r*kin + k] : 0.f);
}

__global__ void w1t_k(const float* __restrict__ W1, float* __restrict__ w1t)
{
  int i = blockIdx.x*256 + threadIdx.x;
  if (i < 1024) w1t[i] = W1[(size_t)i*513 + 512];
}

// Wf = W1h @ W3 (1024x1024, f32 accum, bf16 out). Tile 64x64, K-chunk 64.
__global__ void wf_k(const float* __restrict__ W1, const float* __restrict__ W3,
                     bf16* __restrict__ Wfb)
{
  __shared__ float At[64][64];
  __shared__ float Bt[64][65];
  const int i0 = blockIdx.y*64, j0 = blockIdx.x*64;
  const int tid = threadIdx.x;
  const int ty = tid >> 4, tx = tid & 15;
  float acc[4][4] = {};
  for (int kc = 0; kc < 512; kc += 64){
#pragma unroll
    for (int t = 0; t < 16; ++t){
      int idx = t*256 + tid;
      int r = idx >> 6, k = idx & 63;
      At[r][k] = W1[(size_t)(i0 + r)*513 + kc + k];
      Bt[r][k] = W3[(size_t)(kc + r)*1024 + j0 + k];
    }
    __syncthreads();
#pragma unroll 8
    for (int k = 0; k < 64; ++k){
      float a[4], b[4];
#pragma unroll
      for (int ii = 0; ii < 4; ++ii) a[ii] = At[ty*4 + ii][k];
#pragma unroll
      for (int jj = 0; jj < 4; ++jj) b[jj] = Bt[k][tx*4 + jj];
#pragma unroll
      for (int ii = 0; ii < 4; ++ii)
#pragma unroll
        for (int jj = 0; jj < 4; ++jj) acc[ii][jj] += a[ii]*b[jj];
    }
    __syncthreads();
  }
#pragma unroll
  for (int ii = 0; ii < 4; ++ii)
#pragma unroll
    for (int jj = 0; jj < 4; ++jj)
      Wfb[(size_t)(i0 + ty*4 + ii)*1024 + j0 + tx*4 + jj] = __float2bfloat16(acc[ii][jj]);
}

// bf3 = W1h @ b3 (1024 f32)
__global__ void bf3_k(const float* __restrict__ W1, const float* __restrict__ b3,
                      float* __restrict__ bf3)
{
  int i = blockIdx.x*256 + threadIdx.x;
  if (i < 1024){
    float acc = 0.f;
    for (int c = 0; c < 512; ++c) acc += W1[(size_t)i*513 + c]*b3[c];
    bf3[i] = acc;
  }
}

// Wc3 row R = n16*128 + g*32 + c; hidden col hc = n16*32 + c.
// K: [0:512]=h-part, [512:1024]=x-part. g=0:r g=1:z g=2:hn=[Whh_n|0] g=3:in=[0|Wih_n].
__global__ void wc3_k(const float* __restrict__ Wih, const float* __restrict__ Whh,
                      const float* __restrict__ bih, const float* __restrict__ bhh,
                      bf16* __restrict__ Wc3, float* __restrict__ bcb3)
{
  int idx = blockIdx.x*256 + threadIdx.x;
  if (idx >= 2048*1024) return;
  int R = idx >> 10, k = idx & 1023;
  int n16 = R >> 7, g = (R >> 5) & 3, c = R & 31;
  int hc = n16*32 + c;
  float v;
  if      (g == 0) v = (k < 512) ? Whh[(size_t)hc*512 + k]        : Wih[(size_t)hc*512 + k - 512];
  else if (g == 1) v = (k < 512) ? Whh[(size_t)(512+hc)*512 + k]  : Wih[(size_t)(512+hc)*512 + k - 512];
  else if (g == 2) v = (k < 512) ? Whh[(size_t)(1024+hc)*512 + k] : 0.f;
  else             v = (k < 512) ? 0.f                             : Wih[(size_t)(1024+hc)*512 + k - 512];
  Wc3[idx] = __float2bfloat16(v);
  if (k == 0){
    if      (g == 0) bcb3[R] = bih[hc] + bhh[hc];
    else if (g == 1) bcb3[R] = bih[512 + hc] + bhh[512 + hc];
    else if (g == 2) bcb3[R] = bhh[1024 + hc];
    else             bcb3[R] = bih[1024 + hc];
  }
}

__global__ void init_k(unsigned* __restrict__ cnts)
{
  int idx = blockIdx.x*256 + threadIdx.x;
  if (idx < 16*128) cnts[idx] = 0u;
}

extern "C" void kernel_launch(void* const* d_in, const int* in_sizes, int n_in,
                              void* d_out, int out_size, void* d_ws, size_t ws_size,
                              hipStream_t stream)
{
  const float* x    = (const float*)d_in[0];
  const float* ts   = (const float*)d_in[1];
  const float* Wih  = (const float*)d_in[2];
  const float* Whh  = (const float*)d_in[3];
  const float* bih  = (const float*)d_in[4];
  const float* bhh  = (const float*)d_in[5];
  const float* Wout = (const float*)d_in[6];
  const float* bout = (const float*)d_in[7];
  const float* W1   = (const float*)d_in[8];
  const float* b1   = (const float*)d_in[9];
  const float* W2   = (const float*)d_in[10];
  const float* b2   = (const float*)d_in[11];
  const float* W3   = (const float*)d_in[12];
  const float* b3   = (const float*)d_in[13];

  char* ws = (char*)d_ws;
  size_t off = 0;
  auto alloc = [&](size_t n){ void* p = ws + off; off += (n + 255) & ~(size_t)255; return p; };

  bf16* xbf   = (bf16*)alloc((size_t)B_*T_*D_*2);
  bf16* W1hb  = (bf16*)alloc((size_t)1024*512*2);
  bf16* W2b   = (bf16*)alloc((size_t)1024*1024*2);
  bf16* Wfb   = (bf16*)alloc((size_t)1024*1024*2);
  bf16* W3b   = (bf16*)alloc((size_t)512*1024*2);
  bf16* Woutb = (bf16*)alloc((size_t)128*512*2);
  bf16* Wc3   = (bf16*)alloc((size_t)2048*1024*2);
  float* bcb3 = (float*)alloc((size_t)2048*4);
  float* w1t  = (float*)alloc((size_t)1024*4);
  float* bf3  = (float*)alloc((size_t)1024*4);
  bf16* wbuf  = (bf16*)alloc((size_t)B_*H_*2);
  bf16* hbuf  = (bf16*)alloc((size_t)B_*H_*2);
  bf16* z1buf = (bf16*)alloc((size_t)B_*1024*2);
  bf16* z2buf = (bf16*)alloc((size_t)B_*1024*2);
  bf16* zbuf  = (bf16*)alloc((size_t)B_*1024*2);
  unsigned* cnts = (unsigned*)alloc((size_t)16*128*4);

  auto conv = [&](const float* in, bf16* out, int rows, int kin, int kout){
    int n = rows*kout;
    conv_k<<<(n + 255)/256, 256, 0, stream>>>(in, out, rows, kin, kout);
  };
  conv(x, xbf, B_*T_, D_, D_);
  conv(W1, W1hb, 1024, 513, 512);   // col 512 handled via w1t rank-1 term
  conv(W2, W2b, 1024, 1024, 1024);
  conv(W3, W3b, 512, 1024, 1024);
  conv(Wout, Woutb, 128, 512, 512);
  w1t_k<<<4, 256, 0, stream>>>(W1, w1t);
  wf_k<<<dim3(16,16), 256, 0, stream>>>(W1, W3, Wfb);
  bf3_k<<<4, 256, 0, stream>>>(W1, b3, bf3);
  wc3_k<<<(2048*1024)/256, 256, 0, stream>>>(Wih, Whh, bih, bhh, Wc3, bcb3);
  init_k<<<8, 256, 0, stream>>>(cnts);

  (void)hipFuncSetAttribute((const void*)persist_k,
                            hipFuncAttributeMaxDynamicSharedMemorySize, 66560);
  persist_k<<<256, 256, 66560, stream>>>(
      W1hb, W2b, Wfb, W3b, Woutb, Wc3, xbf,
      b1, b2, b3, bout, bcb3, w1t, bf3, ts,
      wbuf, hbuf, z1buf, z2buf, zbuf, cnts, (float*)d_out);
}

// Round 9
// 1565.111 us; speedup vs baseline: 2.7012x; 1.1640x over previous
//
#include <hip/hip_runtime.h>
#include <hip/hip_bf16.h>
#include <stdint.h>

// RecognitionODEGRU R15 — R14 + XCD-local data path (MALL handshake kept).
// Evidence: R9 proved sc0-only staging collapses FETCH (stages become L2-hits;
// sc0 sc1 staging is HBM-latency) and that {MALL counters + sc0 data} is
// CORRECT; it lost only on streamed-weight L2 thrash, which R12/R14 removed
// (W2/Wf in registers). R15 groups each chain's 16 blocks on one XCD:
// bId = (mb&7) + 8*nb + 128*(mb>>3)  -> XCD = mb%8 under round-robin.
// Runtime-verified via HW_REG_XCC_ID table; mismatch/timeout -> byte-identical
// R14 MALL path. Data stores + slab stages sc0-only on fast path; counters,
// protocol, RK4-in-transformed-domain (Wf = W1h@W3) unchanged from R14.
//
// Shapes: B=512, T=8, D=512, H=512, NSTEPS=4.
// d_out: outs[-1] (512,128) | h (512,512) | c=zeros (512,512), f32.

#define B_ 512
#define T_ 8
#define H_ 512
#define D_ 512

typedef short short8 __attribute__((ext_vector_type(8)));
typedef float f32x4 __attribute__((ext_vector_type(4)));
typedef __hip_bfloat16 bf16;
typedef unsigned long long u64;

__device__ __forceinline__ float sigm(float x){ return 1.f/(1.f+__expf(-x)); }

#define MFMA16(a,b,c) __builtin_amdgcn_mfma_f32_16x16x32_bf16((a),(b),(c),0,0,0)
#define ALD4(p)   __hip_atomic_load((p), __ATOMIC_RELAXED, __HIP_MEMORY_SCOPE_AGENT)

__device__ __forceinline__ void wait_ge(unsigned* c, unsigned tgt, int* dead){
  if (threadIdx.x == 0){
    if (!*dead){
      int it = 0;
      while (ALD4(c) < tgt){
        __builtin_amdgcn_s_sleep(1);
        if (++it > 50000000){ *dead = 1; break; }  // terminate visibly, no hang
      }
    }
  }
  __syncthreads();
}
__device__ __forceinline__ void publish(unsigned* c){
  __builtin_amdgcn_s_waitcnt(0);   // each wave drains its stores (to L2 on fast path) first
  __syncthreads();
  if (threadIdx.x == 0)
    __hip_atomic_fetch_add(c, 1u, __ATOMIC_RELAXED, __HIP_MEMORY_SCOPE_AGENT);
}

// Data stores: fast = sc0-only (terminate in shared XCD L2), slow = agent/MALL.
template<bool L2C>
__device__ __forceinline__ void ast8c(void* p, u64 v){
  if (L2C) asm volatile("global_store_dwordx2 %0, %1, off sc0" :: "v"(p), "v"(v) : "memory");
  else     __hip_atomic_store((u64*)p, v, __ATOMIC_RELAXED, __HIP_MEMORY_SCOPE_AGENT);
}

// Coherent slab stage: CH 16B-chunks/thread, 2^SH chunks per row.
// L2C: sc0-only (XCD-local shared L2 hit). !L2C: sc0 sc1 (MALL/HBM path).
template<int CH, int SH, bool L2C>
__device__ __forceinline__ void stageC16(bf16* lds, int lstr, const bf16* g, int gstr){
  f32x4 tmp[CH];
#pragma unroll
  for (int j = 0; j < CH; ++j){
    int idx = j*256 + threadIdx.x;
    const bf16* p = g + (size_t)(idx >> SH)*gstr + (size_t)(idx & ((1<<SH)-1))*8;
    if (L2C) asm volatile("global_load_dwordx4 %0, %1, off sc0"     : "=v"(tmp[j]) : "v"(p));
    else     asm volatile("global_load_dwordx4 %0, %1, off sc0 sc1" : "=v"(tmp[j]) : "v"(p));
  }
  asm volatile("s_waitcnt vmcnt(0)" ::: "memory");
  __builtin_amdgcn_sched_barrier(0);   // keep ds_writes below the waitcnt
#pragma unroll
  for (int j = 0; j < CH; ++j){
    int idx = j*256 + threadIdx.x;
    *(f32x4*)&lds[(idx >> SH)*lstr + (idx & ((1<<SH)-1))*8] = tmp[j];
  }
}
// Plain (L2-cached) slab stage: CH 16B-chunks/thread, 2^SH chunks per row.
template<int CH, int SH>
__device__ __forceinline__ void stageP(bf16* lds, int lstr, const bf16* g, size_t gstr){
#pragma unroll
  for (int j = 0; j < CH; ++j){
    int idx = j*256 + threadIdx.x;
    *(short8*)&lds[(idx >> SH)*lstr + (idx & ((1<<SH)-1))*8] =
        *(const short8*)(g + (size_t)(idx >> SH)*gstr + (size_t)(idx & ((1<<SH)-1))*8);
  }
}

__device__ __forceinline__ u64 pk4(float a0, float a1, float a2, float a3){
  union { bf16 h[4]; u64 q; } u;
  u.h[0] = __float2bfloat16(a0); u.h[1] = __float2bfloat16(a1);
  u.h[2] = __float2bfloat16(a2); u.h[3] = __float2bfloat16(a3);
  return u.q;
}

template<bool V> struct BC { static constexpr bool value = V; };

// LDS: slab 32x1032 @0 (66048B) | t0s @66048 | dts @66176 | dead @66304 | fflag @66308
__global__ __launch_bounds__(256, 1) void persist_k(
    const bf16* __restrict__ W1hb, const bf16* __restrict__ W2b,
    const bf16* __restrict__ Wfb,  const bf16* __restrict__ W3b,
    const bf16* __restrict__ Woutb,const bf16* __restrict__ Wc3,
    const bf16* __restrict__ xbf,
    const float* __restrict__ b1,  const float* __restrict__ b2,
    const float* __restrict__ b3,  const float* __restrict__ bout,
    const float* __restrict__ bcb3,const float* __restrict__ w1t,
    const float* __restrict__ bf3, const float* __restrict__ ts,
    bf16* wbuf, bf16* hbuf, bf16* z1buf, bf16* z2buf, bf16* zbuf,
    unsigned* cnts, unsigned* xtab, float* dout)
{
  extern __shared__ char smem[];
  bf16* slab = (bf16*)smem;
  float* t0s = (float*)(smem + 66048);
  float* dts = (float*)(smem + 66176);
  int* dead  = (int*)(smem + 66304);
  int* fflag = (int*)(smem + 66308);

  const int tid = threadIdx.x, lane = tid & 63, wv = tid >> 6;
  const int fr = lane & 15, quad = lane >> 4;
  const int bId = blockIdx.x;
  const int mb = (bId & 7) + 8*(bId >> 7);  // chain — 16 members share XCD mb%8
  const int nb = (bId >> 3) & 15;           // n-block
  const int gm0 = mb * 32;
  const int wm = wv & 1;              // batch half (h-mat/gates)
  const int wn = wv >> 1;             // 16-col half (h-mat/gates)

  unsigned* cz1 = cnts + mb*128;
  unsigned* cz2 = cz1 + 32;
  unsigned* ch  = cz1 + 64;
  unsigned* cg  = cz1 + 96;

  // publish my XCD id early (agent scope — correct under any dispatch)
  unsigned myxcd;
  asm volatile("s_getreg_b32 %0, hwreg(HW_REG_XCC_ID)" : "=s"(myxcd));
  myxcd = (myxcd & 0x7fffffffu) | 0x80000000u;
  if (tid == 0)
    __hip_atomic_store(&xtab[bId], myxcd, __ATOMIC_RELAXED, __HIP_MEMORY_SCOPE_AGENT);

  if (tid < 32){
    float t0 = ts[(gm0 + tid)*T_];
    t0s[tid] = t0; dts[tid] = 0.f;   // timestep 0: t0==t1 -> dt=0 (reference)
  }
  if (tid == 0) *dead = 0;

  // chain XCD-grouping check: fast iff all 16 members report one identical id
  if (tid == 0){
    unsigned ref = 0; int ok = 1;
    for (int j = 0; j < 16; ++j){
      int bj = (mb & 7) + 8*j + 128*(mb >> 3);
      unsigned v; int it = 0;
      do {
        v = ALD4(&xtab[bj]);
        if (!v){
          __builtin_amdgcn_s_sleep(8);
          if (++it > 200000){ ok = 0; break; }
        }
      } while (!v);
      if (!v){ ok = 0; break; }
      if (j == 0) ref = v;
      else if (v != ref){ ok = 0; break; }
    }
    *fflag = ok && (ref != 0);
  }
  __syncthreads();
  const int fastp = *fflag;

  // per-lane constant vectors (4 consecutive output cols: quad*4 + j)
  const int zc0 = 64*nb + 16*wv + quad*4;   // z-domain col base (per-wave)
  const int kc0 = 32*nb + 16*wn + quad*4;   // h-domain col base
  const f32x4 b1v  = *(const f32x4*)&b1[zc0];
  const f32x4 w1tv = *(const f32x4*)&w1t[zc0];
  const f32x4 b2v  = *(const f32x4*)&b2[zc0];
  const f32x4 bf3v = *(const f32x4*)&bf3[zc0];
  const f32x4 b3v  = *(const f32x4*)&b3[kc0];
  f32x4 bcv[4];
#pragma unroll
  for (int g = 0; g < 4; ++g)
    bcv[g] = *(const f32x4*)&bcb3[nb*128 + g*32 + 16*wn + quad*4];
  const f32x4 bov = *(const f32x4*)&bout[16*(nb & 7) + quad*4];

  // weight row pointers
  const bf16* w1p = W1hb  + (size_t)(64*nb + 16*wv + fr)*512  + quad*8;  // hW phase (streamed)
  const bf16* w2p = W2b   + (size_t)(64*nb + 16*wv + fr)*1024 + quad*8;  // -> regs
  const bf16* wfp = Wfb   + (size_t)(64*nb + 16*wv + fr)*1024 + quad*8;  // -> regs
  const bf16* w3p = W3b   + (size_t)(32*nb + 16*wn + fr)*1024 + quad*8;  // h-mat (streamed)
  const bf16* wop = Woutb + (size_t)(16*(nb & 7) + fr)*512 + quad*8;
  const bf16* wcp[4];
#pragma unroll
  for (int g = 0; g < 4; ++g)
    wcp[g] = Wc3 + (size_t)(nb*128 + g*32 + 16*wn + fr)*1024 + quad*8;

  // ===== register-resident weight fragments (loop-invariant) =====
  short8 w2f[32], wff[32];
#pragma unroll
  for (int k = 0; k < 32; ++k) w2f[k] = *(const short8*)(w2p + k*32);
#pragma unroll
  for (int k = 0; k < 32; ++k) wff[k] = *(const short8*)(wfp + k*32);

  // transformed-domain state (per lane: rows fr / 16+fr, cols zc0..+4)
  float hw0[4]={0,0,0,0}, hw1[4]={0,0,0,0};
  float pacc0[4]={0,0,0,0}, pacc1[4]={0,0,0,0};
  float zacc0[4]={0,0,0,0}, zacc1[4]={0,0,0,0};
  float hreg[4]={0,0,0,0};   // h-domain (row wm*16+fr, cols kc0..+4)
  unsigned tz1 = 16, tz2 = 16, tch = 16, tcg = 16;

  auto body = [&](auto FASTC){
    constexpr bool FC = decltype(FASTC)::value;

    // initial z1s (h=0 -> hW=0): z1pre = t0*w1t + b1
    {
      const float t0a = t0s[fr], t0b = t0s[16 + fr];
      float v0[4], v1[4];
#pragma unroll
      for (int j = 0; j < 4; ++j){
        v0[j] = t0a*w1tv[j] + b1v[j];
        v1[j] = t0b*w1tv[j] + b1v[j];
        v0[j] *= sigm(v0[j]); v1[j] *= sigm(v1[j]);
      }
      ast8c<FC>(z1buf + (size_t)(gm0 + fr)*1024 + zc0,      pk4(v0[0],v0[1],v0[2],v0[3]));
      ast8c<FC>(z1buf + (size_t)(gm0 + 16 + fr)*1024 + zc0, pk4(v1[0],v1[1],v1[2],v1[3]));
      publish(cz1);
    }

    for (int s = 0; s < T_; ++s){
      for (int sub = 0; sub < 4; ++sub){
        for (int e = 1; e <= 4; ++e){
          // ===== A: z2 = swish(z1s @ W2^T + b2); ZACC += wgt*z2 =====
          wait_ge(cz1, tz1, dead); tz1 += 16;
          stageC16<16,7,FC>(slab, 1032, z1buf + (size_t)gm0*1024, 1024);
          __syncthreads();
          {
            f32x4 a0 = {0,0,0,0}, a1 = {0,0,0,0};
#pragma unroll
            for (int k = 0; k < 32; ++k){
              a0 = MFMA16(w2f[k], *(const short8*)&slab[fr*1032      + k*32 + quad*8], a0);
              a1 = MFMA16(w2f[k], *(const short8*)&slab[(16+fr)*1032 + k*32 + quad*8], a1);
            }
            const float wgt = (e == 2 || e == 3) ? 2.f : 1.f;
            float s0[4], s1[4];
#pragma unroll
            for (int j = 0; j < 4; ++j){
              float v0 = a0[j] + b2v[j], v1 = a1[j] + b2v[j];
              s0[j] = v0*sigm(v0); s1[j] = v1*sigm(v1);
              zacc0[j] += wgt*s0[j]; zacc1[j] += wgt*s1[j];
            }
            if (sub == 3 && e == 4){
              ast8c<FC>(zbuf + (size_t)(gm0 + fr)*1024 + zc0,      pk4(zacc0[0],zacc0[1],zacc0[2],zacc0[3]));
              ast8c<FC>(zbuf + (size_t)(gm0 + 16 + fr)*1024 + zc0, pk4(zacc1[0],zacc1[1],zacc1[2],zacc1[3]));
#pragma unroll
              for (int j = 0; j < 4; ++j){ zacc0[j] = 0.f; zacc1[j] = 0.f; }
            } else {
              ast8c<FC>(z2buf + (size_t)(gm0 + fr)*1024 + zc0,      pk4(s0[0],s0[1],s0[2],s0[3]));
              ast8c<FC>(z2buf + (size_t)(gm0 + 16 + fr)*1024 + zc0, pk4(s1[0],s1[1],s1[2],s1[3]));
            }
            publish(cz2);
          }
          // ===== B: P = z2s @ Wf^T ; emit z1s_{e+1} (skip at sub3,e4) =====
          if (!(sub == 3 && e == 4)){
            wait_ge(cz2, tz2, dead); tz2 += 16;
            stageC16<16,7,FC>(slab, 1032, z2buf + (size_t)gm0*1024, 1024);
            __syncthreads();
            f32x4 p0 = {0,0,0,0}, p1 = {0,0,0,0};
#pragma unroll
            for (int k = 0; k < 32; ++k){
              p0 = MFMA16(wff[k], *(const short8*)&slab[fr*1032      + k*32 + quad*8], p0);
              p1 = MFMA16(wff[k], *(const short8*)&slab[(16+fr)*1032 + k*32 + quad*8], p1);
            }
            const float dta = dts[fr], dtb = dts[16 + fr];
            const float t0a = t0s[fr], t0b = t0s[16 + fr];
            const float ce = (e <= 2) ? (float)sub + 0.5f : (float)sub + 1.f;
            float v0[4], v1[4];
            if (e < 4){
              const float c = (e == 3) ? 1.f : 0.5f;
              const float wgt = (e == 2 || e == 3) ? 2.f : 1.f;
              if (sub < 3){
#pragma unroll
                for (int j = 0; j < 4; ++j){ pacc0[j] += wgt*p0[j]; pacc1[j] += wgt*p1[j]; }
              }
#pragma unroll
              for (int j = 0; j < 4; ++j){
                v0[j] = hw0[j] + c*dta*(p0[j] + bf3v[j]) + (t0a + dta*ce)*w1tv[j] + b1v[j];
                v1[j] = hw1[j] + c*dtb*(p1[j] + bf3v[j]) + (t0b + dtb*ce)*w1tv[j] + b1v[j];
              }
            } else {   // e==4 (only sub<3): advance hW to next sub-step
#pragma unroll
              for (int j = 0; j < 4; ++j){
                float pa = pacc0[j] + p0[j], pb = pacc1[j] + p1[j];
                hw0[j] += dta*(1.f/6.f)*pa + dta*bf3v[j];
                hw1[j] += dtb*(1.f/6.f)*pb + dtb*bf3v[j];
                pacc0[j] = 0.f; pacc1[j] = 0.f;
                v0[j] = hw0[j] + (t0a + dta*ce)*w1tv[j] + b1v[j];
                v1[j] = hw1[j] + (t0b + dtb*ce)*w1tv[j] + b1v[j];
              }
            }
#pragma unroll
            for (int j = 0; j < 4; ++j){ v0[j] *= sigm(v0[j]); v1[j] *= sigm(v1[j]); }
            ast8c<FC>(z1buf + (size_t)(gm0 + fr)*1024 + zc0,      pk4(v0[0],v0[1],v0[2],v0[3]));
            ast8c<FC>(z1buf + (size_t)(gm0 + 16 + fr)*1024 + zc0, pk4(v1[0],v1[1],v1[2],v1[3]));
            publish(cz1);
          }
        }
      }
      // ===== h-mat: h += dt/6 * ZACC@W3^T + 4dt*b3 =====
      wait_ge(cz2, tz2, dead); tz2 += 16;
      stageC16<16,7,FC>(slab, 1032, zbuf + (size_t)gm0*1024, 1024);
      __syncthreads();
      {
        f32x4 ak = {0,0,0,0};
#pragma unroll 8
        for (int k = 0; k < 32; ++k){
          ak = MFMA16(*(const short8*)(w3p + k*32),
                      *(const short8*)&slab[(wm*16 + fr)*1032 + k*32 + quad*8], ak);
        }
        const int r = wm*16 + fr;
        const float dtv = dts[r];
#pragma unroll
        for (int j = 0; j < 4; ++j)
          hreg[j] = hreg[j] + dtv*(1.f/6.f)*ak[j] + 4.f*dtv*b3v[j];
        ast8c<FC>(hbuf + (size_t)(gm0 + r)*512 + kc0, pk4(hreg[0],hreg[1],hreg[2],hreg[3]));
        publish(ch);
      }
      // ===== gates: [h|x_s] @ Wc3^T ; GRU update =====
      wait_ge(ch, tch, dead); tch += 16;
      stageC16<8,6,FC>(slab, 1032, hbuf + (size_t)gm0*512, 512);
      stageP<8,6>(slab + 512, 1032, xbf + ((size_t)gm0*T_ + s)*512, (size_t)T_*512);
      __syncthreads();
      {
        f32x4 ag[4] = {{0,0,0,0},{0,0,0,0},{0,0,0,0},{0,0,0,0}};
#pragma unroll 4
        for (int k = 0; k < 32; ++k){
          short8 xv = *(const short8*)&slab[(wm*16 + fr)*1032 + k*32 + quad*8];
#pragma unroll
          for (int g = 0; g < 4; ++g)
            ag[g] = MFMA16(*(const short8*)(wcp[g] + k*32), xv, ag[g]);
        }
        const int r = wm*16 + fr;
#pragma unroll
        for (int j = 0; j < 4; ++j){
          float r_ = sigm(ag[0][j] + bcv[0][j]);
          float z_ = sigm(ag[1][j] + bcv[1][j]);
          float hn = ag[2][j] + bcv[2][j];
          float in = ag[3][j] + bcv[3][j];
          float n_ = tanhf(in + r_*hn);
          hreg[j] = (1.f - z_)*n_ + z_*hreg[j];
        }
        ast8c<FC>(wbuf + (size_t)(gm0 + r)*512 + kc0, pk4(hreg[0],hreg[1],hreg[2],hreg[3]));
        if (s == T_-1){   // final h (f32 exact) and c=0
          f32x4 hv; hv[0]=hreg[0]; hv[1]=hreg[1]; hv[2]=hreg[2]; hv[3]=hreg[3];
          *(f32x4*)&dout[(size_t)B_*128 + (size_t)(gm0 + r)*512 + kc0] = hv;
          f32x4 z4 = {0,0,0,0};
          *(f32x4*)&dout[(size_t)B_*128 + (size_t)B_*512 + (size_t)(gm0 + r)*512 + kc0] = z4;
        }
        if (tid < 32){
          float t0n = ts[(gm0 + tid)*T_ + s];
          float t1  = (s < T_-1) ? ts[(gm0 + tid)*T_ + s + 1] : t0n;
          t0s[tid] = t0n; dts[tid] = (t1 - t0n)*0.25f;
        }
        publish(cg);
      }
      // ===== hW: hW = h' @ W1h^T ; emit z1s for next timestep =====
      if (s < T_-1){
        wait_ge(cg, tcg, dead); tcg += 16;
        stageC16<8,6,FC>(slab, 520, wbuf + (size_t)gm0*512, 512);
        __syncthreads();
        f32x4 a0 = {0,0,0,0}, a1 = {0,0,0,0};
#pragma unroll 4
        for (int k = 0; k < 16; ++k){
          short8 wt = *(const short8*)(w1p + k*32);
          a0 = MFMA16(wt, *(const short8*)&slab[fr*520      + k*32 + quad*8], a0);
          a1 = MFMA16(wt, *(const short8*)&slab[(16+fr)*520 + k*32 + quad*8], a1);
        }
        const float t0a = t0s[fr], t0b = t0s[16 + fr];
        float v0[4], v1[4];
#pragma unroll
        for (int j = 0; j < 4; ++j){
          hw0[j] = a0[j]; hw1[j] = a1[j];
          v0[j] = hw0[j] + t0a*w1tv[j] + b1v[j];
          v1[j] = hw1[j] + t0b*w1tv[j] + b1v[j];
          v0[j] *= sigm(v0[j]); v1[j] *= sigm(v1[j]);
        }
        ast8c<FC>(z1buf + (size_t)(gm0 + fr)*1024 + zc0,      pk4(v0[0],v0[1],v0[2],v0[3]));
        ast8c<FC>(z1buf + (size_t)(gm0 + 16 + fr)*1024 + zc0, pk4(v1[0],v1[1],v1[2],v1[3]));
        publish(cz1);
      }
    }
    // final stage for out-matmul (h' in wbuf)
    wait_ge(cg, tcg, dead); tcg += 16;
    stageC16<8,6,FC>(slab, 520, wbuf + (size_t)gm0*512, 512);
    __syncthreads();
  };
  if (fastp) body(BC<true>{}); else body(BC<false>{});

  // ===== final: out = h' @ Wout^T + bout (h,c written in last gates) =====
  if (nb < 8 && wv < 2){   // 8 n-blocks x 16 cols cover the 128 outs
    f32x4 ao = {0,0,0,0};
#pragma unroll 4
    for (int k = 0; k < 16; ++k){
      ao = MFMA16(*(const short8*)(wop + k*32),
                  *(const short8*)&slab[(wv*16 + fr)*520 + k*32 + quad*8], ao);
    }
    f32x4 o;
#pragma unroll
    for (int j = 0; j < 4; ++j) o[j] = ao[j] + bov[j];
    *(f32x4*)&dout[(size_t)(gm0 + wv*16 + fr)*128 + 16*nb + quad*4] = o;
  }
}

// ---- prolog kernels ----
__global__ void conv_k(const float* __restrict__ in, bf16* __restrict__ out,
                       int rows, int kin, int kout)
{
  int idx = blockIdx.x*256 + threadIdx.x;
  if (idx >= rows*kout) return;
  int r = idx / kout, k = idx - r*kout;
  out[idx] = __float2bfloat16(k < kin ? in[(size_t)r*kin + k] : 0.f);
}

__global__ void w1t_k(const float* __restrict__ W1, float* __restrict__ w1t)
{
  int i = blockIdx.x*256 + threadIdx.x;
  if (i < 1024) w1t[i] = W1[(size_t)i*513 + 512];
}

// Wf = W1h @ W3 (1024x1024, f32 accum, bf16 out). Tile 64x64, K-chunk 64.
__global__ void wf_k(const float* __restrict__ W1, const float* __restrict__ W3,
                     bf16* __restrict__ Wfb)
{
  __shared__ float At[64][64];
  __shared__ float Bt[64][65];
  const int i0 = blockIdx.y*64, j0 = blockIdx.x*64;
  const int tid = threadIdx.x;
  const int ty = tid >> 4, tx = tid & 15;
  float acc[4][4] = {};
  for (int kc = 0; kc < 512; kc += 64){
#pragma unroll
    for (int t = 0; t < 16; ++t){
      int idx = t*256 + tid;
      int r = idx >> 6, k = idx & 63;
      At[r][k] = W1[(size_t)(i0 + r)*513 + kc + k];
      Bt[r][k] = W3[(size_t)(kc + r)*1024 + j0 + k];
    }
    __syncthreads();
#pragma unroll 8
    for (int k = 0; k < 64; ++k){
      float a[4], b[4];
#pragma unroll
      for (int ii = 0; ii < 4; ++ii) a[ii] = At[ty*4 + ii][k];
#pragma unroll
      for (int jj = 0; jj < 4; ++jj) b[jj] = Bt[k][tx*4 + jj];
#pragma unroll
      for (int ii = 0; ii < 4; ++ii)
#pragma unroll
        for (int jj = 0; jj < 4; ++jj) acc[ii][jj] += a[ii]*b[jj];
    }
    __syncthreads();
  }
#pragma unroll
  for (int ii = 0; ii < 4; ++ii)
#pragma unroll
    for (int jj = 0; jj < 4; ++jj)
      Wfb[(size_t)(i0 + ty*4 + ii)*1024 + j0 + tx*4 + jj] = __float2bfloat16(acc[ii][jj]);
}

// bf3 = W1h @ b3 (1024 f32)
__global__ void bf3_k(const float* __restrict__ W1, const float* __restrict__ b3,
                      float* __restrict__ bf3)
{
  int i = blockIdx.x*256 + threadIdx.x;
  if (i < 1024){
    float acc = 0.f;
    for (int c = 0; c < 512; ++c) acc += W1[(size_t)i*513 + c]*b3[c];
    bf3[i] = acc;
  }
}

// Wc3 row R = n16*128 + g*32 + c; hidden col hc = n16*32 + c.
// K: [0:512]=h-part, [512:1024]=x-part. g=0:r g=1:z g=2:hn=[Whh_n|0] g=3:in=[0|Wih_n].
__global__ void wc3_k(const float* __restrict__ Wih, const float* __restrict__ Whh,
                      const float* __restrict__ bih, const float* __restrict__ bhh,
                      bf16* __restrict__ Wc3, float* __restrict__ bcb3)
{
  int idx = blockIdx.x*256 + threadIdx.x;
  if (idx >= 2048*1024) return;
  int R = idx >> 10, k = idx & 1023;
  int n16 = R >> 7, g = (R >> 5) & 3, c = R & 31;
  int hc = n16*32 + c;
  float v;
  if      (g == 0) v = (k < 512) ? Whh[(size_t)hc*512 + k]        : Wih[(size_t)hc*512 + k - 512];
  else if (g == 1) v = (k < 512) ? Whh[(size_t)(512+hc)*512 + k]  : Wih[(size_t)(512+hc)*512 + k - 512];
  else if (g == 2) v = (k < 512) ? Whh[(size_t)(1024+hc)*512 + k] : 0.f;
  else             v = (k < 512) ? 0.f                             : Wih[(size_t)(1024+hc)*512 + k - 512];
  Wc3[idx] = __float2bfloat16(v);
  if (k == 0){
    if      (g == 0) bcb3[R] = bih[hc] + bhh[hc];
    else if (g == 1) bcb3[R] = bih[512 + hc] + bhh[512 + hc];
    else if (g == 2) bcb3[R] = bhh[1024 + hc];
    else             bcb3[R] = bih[1024 + hc];
  }
}

__global__ void init_k(unsigned* __restrict__ cnts, unsigned* __restrict__ xtab)
{
  int idx = blockIdx.x*256 + threadIdx.x;
  if (idx < 16*128) cnts[idx] = 0u;
  if (idx < 256) xtab[idx] = 0u;
}

extern "C" void kernel_launch(void* const* d_in, const int* in_sizes, int n_in,
                              void* d_out, int out_size, void* d_ws, size_t ws_size,
                              hipStream_t stream)
{
  const float* x    = (const float*)d_in[0];
  const float* ts   = (const float*)d_in[1];
  const float* Wih  = (const float*)d_in[2];
  const float* Whh  = (const float*)d_in[3];
  const float* bih  = (const float*)d_in[4];
  const float* bhh  = (const float*)d_in[5];
  const float* Wout = (const float*)d_in[6];
  const float* bout = (const float*)d_in[7];
  const float* W1   = (const float*)d_in[8];
  const float* b1   = (const float*)d_in[9];
  const float* W2   = (const float*)d_in[10];
  const float* b2   = (const float*)d_in[11];
  const float* W3   = (const float*)d_in[12];
  const float* b3   = (const float*)d_in[13];

  char* ws = (char*)d_ws;
  size_t off = 0;
  auto alloc = [&](size_t n){ void* p = ws + off; off += (n + 255) & ~(size_t)255; return p; };

  bf16* xbf   = (bf16*)alloc((size_t)B_*T_*D_*2);
  bf16* W1hb  = (bf16*)alloc((size_t)1024*512*2);
  bf16* W2b   = (bf16*)alloc((size_t)1024*1024*2);
  bf16* Wfb   = (bf16*)alloc((size_t)1024*1024*2);
  bf16* W3b   = (bf16*)alloc((size_t)512*1024*2);
  bf16* Woutb = (bf16*)alloc((size_t)128*512*2);
  bf16* Wc3   = (bf16*)alloc((size_t)2048*1024*2);
  float* bcb3 = (float*)alloc((size_t)2048*4);
  float* w1t  = (float*)alloc((size_t)1024*4);
  float* bf3  = (float*)alloc((size_t)1024*4);
  bf16* wbuf  = (bf16*)alloc((size_t)B_*H_*2);
  bf16* hbuf  = (bf16*)alloc((size_t)B_*H_*2);
  bf16* z1buf = (bf16*)alloc((size_t)B_*1024*2);
  bf16* z2buf = (bf16*)alloc((size_t)B_*1024*2);
  bf16* zbuf  = (bf16*)alloc((size_t)B_*1024*2);
  unsigned* cnts = (unsigned*)alloc((size_t)16*128*4);
  unsigned* xtab = (unsigned*)alloc((size_t)256*4);

  auto conv = [&](const float* in, bf16* out, int rows, int kin, int kout){
    int n = rows*kout;
    conv_k<<<(n + 255)/256, 256, 0, stream>>>(in, out, rows, kin, kout);
  };
  conv(x, xbf, B_*T_, D_, D_);
  conv(W1, W1hb, 1024, 513, 512);   // col 512 handled via w1t rank-1 term
  conv(W2, W2b, 1024, 1024, 1024);
  conv(W3, W3b, 512, 1024, 1024);
  conv(Wout, Woutb, 128, 512, 512);
  w1t_k<<<4, 256, 0, stream>>>(W1, w1t);
  wf_k<<<dim3(16,16), 256, 0, stream>>>(W1, W3, Wfb);
  bf3_k<<<4, 256, 0, stream>>>(W1, b3, bf3);
  wc3_k<<<(2048*1024)/256, 256, 0, stream>>>(Wih, Whh, bih, bhh, Wc3, bcb3);
  init_k<<<8, 256, 0, stream>>>(cnts, xtab);

  (void)hipFuncSetAttribute((const void*)persist_k,
                            hipFuncAttributeMaxDynamicSharedMemorySize, 66560);
  persist_k<<<256, 256, 66560, stream>>>(
      W1hb, W2b, Wfb, W3b, Woutb, Wc3, xbf,
      b1, b2, b3, bout, bcb3, w1t, bf3, ts,
      wbuf, hbuf, z1buf, z2buf, zbuf, cnts, xtab, (float*)d_out);
}